// Round 1
// baseline (735.501 us; speedup 1.0000x reference)
//
#include <hip/hip_runtime.h>

#define C 10

__device__ inline float waveSum(float v) {
  #pragma unroll
  for (int off = 32; off > 0; off >>= 1) v += __shfl_down(v, off, 64);
  return v;
}
__device__ inline float waveMin(float v) {
  #pragma unroll
  for (int off = 32; off > 0; off >>= 1) v = fminf(v, __shfl_down(v, off, 64));
  return v;
}
__device__ inline float waveMax(float v) {
  #pragma unroll
  for (int off = 32; off > 0; off >>= 1) v = fmaxf(v, __shfl_down(v, off, 64));
  return v;
}

// --- kernel 0: label of sample 0 (reference's jnp.argmax(y) over flattened array
// hits the first 1.0, which is in row 0), plus init umin to +inf bits.
__global__ void k_init(const float* __restrict__ y, int* label_ptr, unsigned* umin_bits) {
  float mx = y[0];
  int am = 0;
  #pragma unroll
  for (int c = 1; c < C; ++c) {
    float v = y[c];
    if (v > mx) { mx = v; am = c; }
  }
  *label_ptr = am;
  *umin_bits = 0x7f800000u;  // +inf
}

__device__ inline void process_row(const float* p, const float* yv, int label0,
                                   float& unc, float& ce, float& focal, bool& acc) {
  float mx = p[0];
  int am = 0;
  #pragma unroll
  for (int c = 1; c < C; ++c) {
    if (p[c] > mx) { mx = p[c]; am = c; }  // strict > keeps first max (jnp.argmax)
  }
  float u = 0.f, cl = 0.f, fl = 0.f;
  #pragma unroll
  for (int c = 0; c < C; ++c) {
    float pc = p[c];
    float lp10 = logf(fmaxf(pc, 1e-10f));          // EPS for entropy
    float lp8 = fmaxf(lp10, -18.420681f);          // log(max(p,1e-8)) == max(log(max(p,1e-10)), log(1e-8))
    u -= pc * lp10;
    float t = yv[c] * lp8;
    cl -= t;
    fl -= t * (1.0f - pc);
  }
  unc = u; ce = cl; focal = fl; acc = (am == label0);
}

// --- pass 1: per-sample entropy/acc/focal/ce; 2 rows per thread (80B = 5 float4, aligned)
__global__ __launch_bounds__(256) void pass1(
    const float4* __restrict__ probs4, const float4* __restrict__ y4,
    float2* __restrict__ us2, const int* __restrict__ label_ptr,
    float* ce_acc, float* focal_acc, unsigned* umin_bits, unsigned* umax_bits,
    int npairs) {
  int pair = blockIdx.x * 256 + threadIdx.x;
  float ce = 0.f, fl = 0.f;
  float umin = __uint_as_float(0x7f800000u), umax = 0.f;
  if (pair < npairs) {
    int label0 = *label_ptr;
    float P[2 * C], Y[2 * C];
    const float4* pp = probs4 + (size_t)pair * 5;
    const float4* yy = y4 + (size_t)pair * 5;
    #pragma unroll
    for (int q = 0; q < 5; ++q) {
      float4 a = pp[q];
      P[4 * q] = a.x; P[4 * q + 1] = a.y; P[4 * q + 2] = a.z; P[4 * q + 3] = a.w;
      float4 b = yy[q];
      Y[4 * q] = b.x; Y[4 * q + 1] = b.y; Y[4 * q + 2] = b.z; Y[4 * q + 3] = b.w;
    }
    float u0, c0, f0, u1, c1, f1;
    bool a0, a1;
    process_row(P, Y, label0, u0, c0, f0, a0);
    process_row(P + C, Y + C, label0, u1, c1, f1, a1);
    // pack acc into sign bit (unc >= 0 always; sign set == inaccurate)
    unsigned s0 = __float_as_uint(u0) | (a0 ? 0u : 0x80000000u);
    unsigned s1 = __float_as_uint(u1) | (a1 ? 0u : 0x80000000u);
    us2[pair] = make_float2(__uint_as_float(s0), __uint_as_float(s1));
    ce = c0 + c1; fl = f0 + f1;
    umin = fminf(u0, u1); umax = fmaxf(u0, u1);
  }
  ce = waveSum(ce); fl = waveSum(fl);
  umin = waveMin(umin); umax = waveMax(umax);
  __shared__ float sc[4], sf[4], sn[4], sx[4];
  int wid = threadIdx.x >> 6, lane = threadIdx.x & 63;
  if (lane == 0) { sc[wid] = ce; sf[wid] = fl; sn[wid] = umin; sx[wid] = umax; }
  __syncthreads();
  if (threadIdx.x == 0) {
    float tc = sc[0] + sc[1] + sc[2] + sc[3];
    float tf = sf[0] + sf[1] + sf[2] + sf[3];
    float mn = fminf(fminf(sn[0], sn[1]), fminf(sn[2], sn[3]));
    float mx = fmaxf(fmaxf(sx[0], sx[1]), fmaxf(sx[2], sx[3]));
    atomicAdd(ce_acc, tc);
    atomicAdd(focal_acc, tf);
    atomicMin(umin_bits, __float_as_uint(mn));  // valid: non-negative floats order as uints
    atomicMax(umax_bits, __float_as_uint(mx));
  }
}

// --- pass 2: bucket each sample into 22 bins x 4 categories.
// LDS histogram: per-lane private column -> no atomics, no bank conflicts.
__global__ __launch_bounds__(64) void pass2(
    const float4* __restrict__ us4, int n4,
    const unsigned* __restrict__ umin_bits, const unsigned* __restrict__ umax_bits,
    float* __restrict__ g_hist) {
  __shared__ float hist[88 * 64];  // [cat*22+j][lane], 22528 B
  const int lane = threadIdx.x;
  for (int r = 0; r < 88; ++r) hist[r * 64 + lane] = 0.f;
  __syncthreads();
  const float umin = __uint_as_float(*umin_bits);
  const float delta = __uint_as_float(*umax_bits) - umin;
  const int stride = gridDim.x * 64;
  for (int i = blockIdx.x * 64 + lane; i < n4; i += stride) {
    float4 v = us4[i];
    float vv[4] = {v.x, v.y, v.z, v.w};
    #pragma unroll
    for (int q = 0; q < 4; ++q) {
      unsigned b = __float_as_uint(vv[q]);
      int rowBase = (b >> 31) ? 44 : 0;  // acc -> rows 0..43, inacc -> 44..87
      float u = __uint_as_float(b & 0x7fffffffu);
      float e = u * 0.43429448f;  // 1/log(10)
      float num = e * 0.9f;
      float den = fmaxf((1.0f - e) * 0.1f, 1e-10f);
      float frac = fmaxf(num / den, 1e-10f);
      float x = logf(frac) * 100.0f;  // log(frac)/TEMP
      float s = 1.0f / (1.0f + expf(-x));
      float t = tanhf(u);
      float wc = (1.0f - s) * (1.0f - t);
      float wu = s * t;
      int j = 0;  // j = #{k : th_k < u}; le[k] <=> k >= j
      #pragma unroll
      for (int k = 0; k < 21; ++k) j += (u > (umin + (k * 0.05f) * delta)) ? 1 : 0;
      hist[(rowBase + j) * 64 + lane] += wc;
      hist[(rowBase + 22 + j) * 64 + lane] += wu;
    }
  }
  __syncthreads();
  // tree-reduce 64 columns per row
  #pragma unroll
  for (int st = 32; st >= 1; st >>= 1) {
    for (int idx = lane; idx < 88 * st; idx += 64) {
      int r = idx / st, c = idx - r * st;
      hist[r * 64 + c] += hist[r * 64 + c + st];
    }
    __syncthreads();
  }
  for (int r = lane; r < 88; r += 64) atomicAdd(&g_hist[r], hist[r * 64]);
}

// --- final: prefix/suffix sums over bins -> avu -> trapezoid -> outputs
__global__ void k_final(const float* __restrict__ g_hist, const float* ce_acc,
                        const float* focal_acc, float* __restrict__ out, float invN) {
  float H0[22], H1[22], H2[22], H3[22];
  float totAU = 0.f, totIU = 0.f;
  for (int j = 0; j < 22; ++j) {
    H0[j] = g_hist[j];
    H1[j] = g_hist[22 + j];
    H2[j] = g_hist[44 + j];
    H3[j] = g_hist[66 + j];
    totAU += H1[j];
    totIU += H3[j];
  }
  float n_ac = 0.f, n_ic = 0.f, n_au = totAU, n_iu = totIU;
  float auc = 0.f, prev = 0.f;
  for (int k = 0; k < 21; ++k) {
    n_ac += H0[k]; n_ic += H2[k];
    n_au -= H1[k]; n_iu -= H3[k];
    float avu = (n_ac + n_iu) / (n_ac + n_au + n_ic + n_iu + 1e-10f);
    if (k > 0) auc += (avu + prev) * 0.5f * 0.05f;
    prev = avu;
  }
  out[0] = -logf(fmaxf(auc, 1e-10f)) + (*focal_acc) * invN;
  out[1] = (*ce_acc) * invN;
}

extern "C" void kernel_launch(void* const* d_in, const int* in_sizes, int n_in,
                              void* d_out, int out_size, void* d_ws, size_t ws_size,
                              hipStream_t stream) {
  const float* probs = (const float*)d_in[0];
  const float* y = (const float*)d_in[1];
  float* out = (float*)d_out;
  const int N = in_sizes[0] / C;

  // workspace layout (floats): [0]=label0(int) [1]=umin_bits [2]=umax_bits
  // [3]=ce_sum [4]=focal_sum [8..96)=hist[88] [96..96+N)=unc_signed
  float* wsf = (float*)d_ws;
  int* label_ptr = (int*)wsf;
  unsigned* umin_bits = (unsigned*)(wsf + 1);
  unsigned* umax_bits = (unsigned*)(wsf + 2);
  float* ce_acc = wsf + 3;
  float* focal_acc = wsf + 4;
  float* g_hist = wsf + 8;
  float* us = wsf + 96;  // 384B offset -> float4 aligned

  hipMemsetAsync(d_ws, 0, 512, stream);  // zero header + hist
  k_init<<<1, 1, 0, stream>>>(y, label_ptr, umin_bits);

  int npairs = N / 2;
  int blocks1 = (npairs + 255) / 256;
  pass1<<<blocks1, 256, 0, stream>>>((const float4*)probs, (const float4*)y,
                                     (float2*)us, label_ptr, ce_acc, focal_acc,
                                     umin_bits, umax_bits, npairs);

  int n4 = N / 4;
  pass2<<<2048, 64, 0, stream>>>((const float4*)us, n4, umin_bits, umax_bits, g_hist);

  k_final<<<1, 1, 0, stream>>>(g_hist, ce_acc, focal_acc, out, 1.0f / (float)N);
}

// Round 2
// 511.611 us; speedup vs baseline: 1.4376x; 1.4376x over previous
//
#include <hip/hip_runtime.h>

#define C 10
#define TILE 512   // rows per pass1 block (N = 4194304 = 8192 * 512, exact)

__device__ __forceinline__ float waveSum(float v) {
#pragma unroll
  for (int o = 32; o > 0; o >>= 1) v += __shfl_down(v, o, 64);
  return v;
}
__device__ __forceinline__ float waveMin(float v) {
#pragma unroll
  for (int o = 32; o > 0; o >>= 1) v = fminf(v, __shfl_down(v, o, 64));
  return v;
}
__device__ __forceinline__ float waveMax(float v) {
#pragma unroll
  for (int o = 32; o > 0; o >>= 1) v = fmaxf(v, __shfl_down(v, o, 64));
  return v;
}

// async global->LDS, 16B per lane; LDS dest is wave-uniform base + lane*16,
// our idx = k*256 + tid is lane-contiguous within each wave -> valid pattern (m97).
#define GLD16(gp, lp)                                             \
  __builtin_amdgcn_global_load_lds(                               \
      (__attribute__((address_space(1))) void*)(gp),              \
      (__attribute__((address_space(3))) void*)(lp), 16, 0, 0)

// ---------------- pass 1: entropy/argmax/ce/focal per row, coalesced via LDS staging
__global__ __launch_bounds__(256, 6) void pass1(
    const float* __restrict__ probs, const float* __restrict__ y,
    float* __restrict__ us,
    unsigned* __restrict__ uminSlots, unsigned* __restrict__ umaxSlots,
    float* __restrict__ ceSlots, float* __restrict__ focalSlots) {
  __shared__ float buf[TILE * C];  // 20480 B, reused for probs then y
  __shared__ float red[16];
  const int tid = threadIdx.x;
  const size_t base = (size_t)blockIdx.x * (TILE * C);  // float index of tile

  // stage probs tile (1280 float4s, 5 per thread, coalesced async)
#pragma unroll
  for (int k = 0; k < 5; ++k) {
    int idx = k * 256 + tid;
    GLD16(probs + base + (size_t)idx * 4, (float*)buf + idx * 4);
  }

  // label0 = argmax of flattened y == label of sample 0 (first max). L1-resident.
  int label0 = 0;
  {
    float m = y[0];
#pragma unroll
    for (int c = 1; c < C; ++c) {
      float v = y[c];
      if (v > m) { m = v; label0 = c; }
    }
  }
  __syncthreads();  // drains vmcnt -> probs tile resident

  // rows tid and tid+256 of this tile; keep P in registers
  float P0[C], P1[C];
  {
    const float2* b2 = (const float2*)buf;
#pragma unroll
    for (int j = 0; j < 5; ++j) {
      float2 v = b2[tid * 5 + j];
      P0[2 * j] = v.x; P0[2 * j + 1] = v.y;
    }
#pragma unroll
    for (int j = 0; j < 5; ++j) {
      float2 v = b2[(tid + 256) * 5 + j];
      P1[2 * j] = v.x; P1[2 * j + 1] = v.y;
    }
  }
  int am0 = 0, am1 = 0;
  float m0 = P0[0], m1 = P1[0];
#pragma unroll
  for (int c = 1; c < C; ++c) {  // strict > keeps first max (jnp.argmax)
    if (P0[c] > m0) { m0 = P0[c]; am0 = c; }
    if (P1[c] > m1) { m1 = P1[c]; am1 = c; }
  }
  float u0 = 0.f, u1 = 0.f;
#pragma unroll
  for (int c = 0; c < C; ++c) {
    u0 -= P0[c] * __logf(fmaxf(P0[c], 1e-10f));
    u1 -= P1[c] * __logf(fmaxf(P1[c], 1e-10f));
  }

  __syncthreads();  // all reads of probs tile done -> safe to overwrite
#pragma unroll
  for (int k = 0; k < 5; ++k) {
    int idx = k * 256 + tid;
    GLD16(y + base + (size_t)idx * 4, (float*)buf + idx * 4);
  }
  __syncthreads();

  // y is exactly one-hot: p_label = sum(y*p); ce = -log(max(pl,1e-8)); focal = ce*(1-pl)
  float pl0 = 0.f, pl1 = 0.f;
  {
    const float2* b2 = (const float2*)buf;
#pragma unroll
    for (int j = 0; j < 5; ++j) {
      float2 v = b2[tid * 5 + j];
      pl0 = fmaf(v.x, P0[2 * j], pl0);
      pl0 = fmaf(v.y, P0[2 * j + 1], pl0);
    }
#pragma unroll
    for (int j = 0; j < 5; ++j) {
      float2 v = b2[(tid + 256) * 5 + j];
      pl1 = fmaf(v.x, P1[2 * j], pl1);
      pl1 = fmaf(v.y, P1[2 * j + 1], pl1);
    }
  }
  float ce0 = -__logf(fmaxf(pl0, 1e-8f)), ce1 = -__logf(fmaxf(pl1, 1e-8f));
  float fo0 = ce0 * (1.f - pl0), fo1 = ce1 * (1.f - pl1);

  // write unc with acc packed in sign bit (unc >= 0; sign set == inaccurate)
  size_t rowBase = (size_t)blockIdx.x * TILE;
  us[rowBase + tid] =
      __uint_as_float(__float_as_uint(u0) | ((am0 == label0) ? 0u : 0x80000000u));
  us[rowBase + 256 + tid] =
      __uint_as_float(__float_as_uint(u1) | ((am1 == label0) ? 0u : 0x80000000u));

  // block reduce ce/focal/min/max, then spread-slot atomics (<=128 ops per address)
  float ce = ce0 + ce1, fo = fo0 + fo1;
  float mn = fminf(u0, u1), mx = fmaxf(u0, u1);
  ce = waveSum(ce); fo = waveSum(fo);
  mn = waveMin(mn); mx = waveMax(mx);
  int wid = tid >> 6, lane = tid & 63;
  if (lane == 0) { red[wid] = ce; red[4 + wid] = fo; red[8 + wid] = mn; red[12 + wid] = mx; }
  __syncthreads();
  if (tid == 0) {
    float tce = red[0] + red[1] + red[2] + red[3];
    float tfo = red[4] + red[5] + red[6] + red[7];
    float tmn = fminf(fminf(red[8], red[9]), fminf(red[10], red[11]));
    float tmx = fmaxf(fmaxf(red[12], red[13]), fmaxf(red[14], red[15]));
    int slot = blockIdx.x & 63;
    atomicAdd(&ceSlots[slot], tce);
    atomicAdd(&focalSlots[slot], tfo);
    atomicMin(&uminSlots[slot], __float_as_uint(tmn));  // nonneg floats order as uints
    atomicMax(&umaxSlots[slot], __float_as_uint(tmx));
  }
}

// ---------------- pass 2: 22-bin x 4-category histogram; per-lane LDS columns,
// 4 waves share columns via ds_add_f32 (lane-indexed -> conflict/contention free).
// Writes per-block partials: NO global atomics.
__global__ __launch_bounds__(256, 4) void pass2(
    const float4* __restrict__ us4, int n4,
    const unsigned* __restrict__ uminSlots, const unsigned* __restrict__ umaxSlots,
    float* __restrict__ gpart) {
  __shared__ float hist[88 * 64];  // [row][lane], 22528 B
  __shared__ float smm[2];
  const int tid = threadIdx.x, lane = tid & 63;
  for (int i = tid; i < 88 * 64; i += 256) hist[i] = 0.f;
  if (tid < 64) {
    float mn = __uint_as_float(uminSlots[tid]);
    float mx = __uint_as_float(umaxSlots[tid]);
    mn = waveMin(mn); mx = waveMax(mx);
    if (tid == 0) { smm[0] = mn; smm[1] = mx; }
  }
  __syncthreads();
  const float umin = smm[0], delta = smm[1] - smm[0];
  float th[21];
#pragma unroll
  for (int k = 0; k < 21; ++k) th[k] = fmaf(0.05f * (float)k, delta, umin);

  const int stride = gridDim.x * 256;
  for (int i = blockIdx.x * 256 + tid; i < n4; i += stride) {
    float4 v = us4[i];
    float vv[4] = {v.x, v.y, v.z, v.w};
#pragma unroll
    for (int q = 0; q < 4; ++q) {
      unsigned b = __float_as_uint(vv[q]);
      int rb = (b >> 31) ? 44 : 0;  // acc rows 0..43, inacc rows 44..87
      float u = __uint_as_float(b & 0x7fffffffu);
      // soft_T: log(num/den) = log(num)-log(den); clamp matches frac clamp
      float e = u * 0.4342944819f;  // u / ln(10)
      float lnum = __logf(e * 0.9f);
      float lden = __logf(fmaxf((1.f - e) * 0.1f, 1e-10f));
      float x = fmaxf(lnum - lden, -23.0258509f) * 100.f;
      float s = __builtin_amdgcn_rcpf(1.f + __expf(-x));              // sigmoid
      float t = 1.f - 2.f * __builtin_amdgcn_rcpf(__expf(2.f * u) + 1.f);  // tanh
      float wc = (1.f - s) * (1.f - t), wu = s * t;
      int j = 0;  // j = #{k: u > th_k}; le[k] <=> k >= j
#pragma unroll
      for (int k = 0; k < 21; ++k) j += (u > th[k]) ? 1 : 0;
      atomicAdd(&hist[(rb + j) * 64 + lane], wc);        // ds_add_f32
      atomicAdd(&hist[(rb + 22 + j) * 64 + lane], wu);
    }
  }
  __syncthreads();
  // tree-reduce 64 columns per row
#pragma unroll
  for (int st = 32; st >= 1; st >>= 1) {
    for (int idx = tid; idx < 88 * st; idx += 256) {
      int r = idx / st, c = idx - r * st;
      hist[r * 64 + c] += hist[r * 64 + c + st];
    }
    __syncthreads();
  }
  for (int r = tid; r < 88; r += 256) gpart[(size_t)blockIdx.x * 88 + r] = hist[r * 64];
}

// ---------------- pass 3: reduce partials + slots, compute avu/auc/outputs
__global__ __launch_bounds__(256) void pass3(
    const float* __restrict__ gpart, int nb,
    const float* __restrict__ ceSlots, const float* __restrict__ focalSlots,
    float* __restrict__ out, float invN) {
  __shared__ float hp[2][88];
  __shared__ float hr[88];
  __shared__ float scf[2];
  int tid = threadIdx.x;
  if (tid < 176) {
    int r = tid % 88, h = tid / 88;
    int half = nb >> 1;
    int b0 = h * half, b1 = b0 + half;
    float s = 0.f;
    for (int b = b0; b < b1; ++b) s += gpart[(size_t)b * 88 + r];
    hp[h][r] = s;
  }
  __syncthreads();
  if (tid < 88) hr[tid] = hp[0][tid] + hp[1][tid];
  if (tid < 64) {
    float ce = ceSlots[tid], fo = focalSlots[tid];
    ce = waveSum(ce); fo = waveSum(fo);
    if (tid == 0) { scf[0] = ce; scf[1] = fo; }
  }
  __syncthreads();
  if (tid == 0) {
    float H0[22], H1[22], H2[22], H3[22];
    float totAU = 0.f, totIU = 0.f;
    for (int j = 0; j < 22; ++j) {
      H0[j] = hr[j]; H1[j] = hr[22 + j]; H2[j] = hr[44 + j]; H3[j] = hr[66 + j];
      totAU += H1[j]; totIU += H3[j];
    }
    float n_ac = 0.f, n_ic = 0.f, n_au = totAU, n_iu = totIU;
    float auc = 0.f, prev = 0.f;
    for (int k = 0; k < 21; ++k) {
      n_ac += H0[k]; n_ic += H2[k];
      n_au -= H1[k]; n_iu -= H3[k];
      float avu = (n_ac + n_iu) / (n_ac + n_au + n_ic + n_iu + 1e-10f);
      if (k > 0) auc += (avu + prev) * 0.5f * 0.05f;
      prev = avu;
    }
    out[0] = -logf(fmaxf(auc, 1e-10f)) + scf[1] * invN;
    out[1] = scf[0] * invN;
  }
}

extern "C" void kernel_launch(void* const* d_in, const int* in_sizes, int n_in,
                              void* d_out, int out_size, void* d_ws, size_t ws_size,
                              hipStream_t stream) {
  const float* probs = (const float*)d_in[0];
  const float* y = (const float*)d_in[1];
  float* out = (float*)d_out;
  const int N = in_sizes[0] / C;

  // ws layout (floats): [0,64) umin slots (uint, init 0xFF...), [64,128) umax slots,
  // [128,192) ce slots, [192,256) focal slots, [256, 256+88*NB2) partials,
  // then us[N] (float4-aligned: (256+88*1024)*4 = 361472 B, /16 exact)
  float* wsf = (float*)d_ws;
  unsigned* uminSlots = (unsigned*)wsf;
  unsigned* umaxSlots = (unsigned*)(wsf + 64);
  float* ceSlots = wsf + 128;
  float* focalSlots = wsf + 192;
  float* gpart = wsf + 256;
  const int NB2 = 1024;
  float* us = wsf + 256 + 88 * NB2;

  hipMemsetAsync(d_ws, 0xFF, 256, stream);           // umin slots -> max uint
  hipMemsetAsync((char*)d_ws + 256, 0, 768, stream); // umax/ce/focal slots -> 0

  pass1<<<N / TILE, 256, 0, stream>>>(probs, y, us, uminSlots, umaxSlots,
                                      ceSlots, focalSlots);
  pass2<<<NB2, 256, 0, stream>>>((const float4*)us, N / 4, uminSlots, umaxSlots, gpart);
  pass3<<<1, 256, 0, stream>>>(gpart, NB2, ceSlots, focalSlots, out, 1.0f / (float)N);
}

// Round 3
// 387.933 us; speedup vs baseline: 1.8960x; 1.3188x over previous
//
#include <hip/hip_runtime.h>

#define C 10
#define TILE 512   // rows per pass1 block (N = 4194304 = 8192 * 512, exact)

__device__ __forceinline__ float waveSum(float v) {
#pragma unroll
  for (int o = 32; o > 0; o >>= 1) v += __shfl_down(v, o, 64);
  return v;
}
__device__ __forceinline__ float waveMin(float v) {
#pragma unroll
  for (int o = 32; o > 0; o >>= 1) v = fminf(v, __shfl_down(v, o, 64));
  return v;
}
__device__ __forceinline__ float waveMax(float v) {
#pragma unroll
  for (int o = 32; o > 0; o >>= 1) v = fmaxf(v, __shfl_down(v, o, 64));
  return v;
}
__device__ __forceinline__ unsigned waveMaxU(unsigned v) {
#pragma unroll
  for (int o = 32; o > 0; o >>= 1) {
    unsigned w = (unsigned)__shfl_down((int)v, o, 64);
    v = v > w ? v : w;
  }
  return v;
}

// async global->LDS, 16B per lane; LDS dest is wave-uniform base + lane*16,
// our idx = k*256 + tid is lane-contiguous within each wave -> valid pattern (m97).
#define GLD16(gp, lp)                                             \
  __builtin_amdgcn_global_load_lds(                               \
      (__attribute__((address_space(1))) void*)(gp),              \
      (__attribute__((address_space(3))) void*)(lp), 16, 0, 0)

// ---------------- pass 1: entropy/argmax/ce/focal per row, coalesced via LDS staging
__global__ __launch_bounds__(256, 6) void pass1(
    const float* __restrict__ probs, const float* __restrict__ y,
    float* __restrict__ us,
    unsigned* __restrict__ uminInvSlots, unsigned* __restrict__ umaxSlots,
    float* __restrict__ ceSlots, float* __restrict__ focalSlots) {
  __shared__ float buf[TILE * C];  // 20480 B, reused for probs then y
  __shared__ float red[16];
  const int tid = threadIdx.x;
  const size_t base = (size_t)blockIdx.x * (TILE * C);  // float index of tile

  // stage probs tile (1280 float4s, 5 per thread, coalesced async)
#pragma unroll
  for (int k = 0; k < 5; ++k) {
    int idx = k * 256 + tid;
    GLD16(probs + base + (size_t)idx * 4, (float*)buf + idx * 4);
  }

  // label0 = argmax of flattened y == label of sample 0 (first max). L1-resident.
  int label0 = 0;
  {
    float m = y[0];
#pragma unroll
    for (int c = 1; c < C; ++c) {
      float v = y[c];
      if (v > m) { m = v; label0 = c; }
    }
  }
  __syncthreads();  // drains vmcnt -> probs tile resident

  // rows tid and tid+256 of this tile; keep P in registers
  float P0[C], P1[C];
  {
    const float2* b2 = (const float2*)buf;
#pragma unroll
    for (int j = 0; j < 5; ++j) {
      float2 v = b2[tid * 5 + j];
      P0[2 * j] = v.x; P0[2 * j + 1] = v.y;
    }
#pragma unroll
    for (int j = 0; j < 5; ++j) {
      float2 v = b2[(tid + 256) * 5 + j];
      P1[2 * j] = v.x; P1[2 * j + 1] = v.y;
    }
  }
  int am0 = 0, am1 = 0;
  float m0 = P0[0], m1 = P1[0];
#pragma unroll
  for (int c = 1; c < C; ++c) {  // strict > keeps first max (jnp.argmax)
    if (P0[c] > m0) { m0 = P0[c]; am0 = c; }
    if (P1[c] > m1) { m1 = P1[c]; am1 = c; }
  }
  float u0 = 0.f, u1 = 0.f;
#pragma unroll
  for (int c = 0; c < C; ++c) {
    u0 -= P0[c] * __logf(fmaxf(P0[c], 1e-10f));
    u1 -= P1[c] * __logf(fmaxf(P1[c], 1e-10f));
  }

  __syncthreads();  // all reads of probs tile done -> safe to overwrite
#pragma unroll
  for (int k = 0; k < 5; ++k) {
    int idx = k * 256 + tid;
    GLD16(y + base + (size_t)idx * 4, (float*)buf + idx * 4);
  }
  __syncthreads();

  // y is exactly one-hot: p_label = sum(y*p); ce = -log(max(pl,1e-8)); focal = ce*(1-pl)
  float pl0 = 0.f, pl1 = 0.f;
  {
    const float2* b2 = (const float2*)buf;
#pragma unroll
    for (int j = 0; j < 5; ++j) {
      float2 v = b2[tid * 5 + j];
      pl0 = fmaf(v.x, P0[2 * j], pl0);
      pl0 = fmaf(v.y, P0[2 * j + 1], pl0);
    }
#pragma unroll
    for (int j = 0; j < 5; ++j) {
      float2 v = b2[(tid + 256) * 5 + j];
      pl1 = fmaf(v.x, P1[2 * j], pl1);
      pl1 = fmaf(v.y, P1[2 * j + 1], pl1);
    }
  }
  float ce0 = -__logf(fmaxf(pl0, 1e-8f)), ce1 = -__logf(fmaxf(pl1, 1e-8f));
  float fo0 = ce0 * (1.f - pl0), fo1 = ce1 * (1.f - pl1);

  // write unc with acc packed in sign bit (unc >= 0; sign set == inaccurate)
  size_t rowBase = (size_t)blockIdx.x * TILE;
  us[rowBase + tid] =
      __uint_as_float(__float_as_uint(u0) | ((am0 == label0) ? 0u : 0x80000000u));
  us[rowBase + 256 + tid] =
      __uint_as_float(__float_as_uint(u1) | ((am1 == label0) ? 0u : 0x80000000u));

  // block reduce ce/focal/min/max, then spread-slot atomics (128 ops per address)
  float ce = ce0 + ce1, fo = fo0 + fo1;
  float mn = fminf(u0, u1), mx = fmaxf(u0, u1);
  ce = waveSum(ce); fo = waveSum(fo);
  mn = waveMin(mn); mx = waveMax(mx);
  int wid = tid >> 6, lane = tid & 63;
  if (lane == 0) { red[wid] = ce; red[4 + wid] = fo; red[8 + wid] = mn; red[12 + wid] = mx; }
  __syncthreads();
  if (tid == 0) {
    float tce = red[0] + red[1] + red[2] + red[3];
    float tfo = red[4] + red[5] + red[6] + red[7];
    float tmn = fminf(fminf(red[8], red[9]), fminf(red[10], red[11]));
    float tmx = fmaxf(fmaxf(red[12], red[13]), fmaxf(red[14], red[15]));
    int slot = blockIdx.x & 63;
    atomicAdd(&ceSlots[slot], tce);
    atomicAdd(&focalSlots[slot], tfo);
    // min via inverted bits (nonneg floats order as uints; slots init to 0)
    atomicMax(&uminInvSlots[slot], ~__float_as_uint(tmn));
    atomicMax(&umaxSlots[slot], __float_as_uint(tmx));
  }
}

// ---------------- pass 2: 22-bin x 4-category histogram; per-lane LDS columns,
// 4 waves share columns via ds_add_f32 (lane-indexed -> conflict/contention free).
// Block partials go to 64 spread slot-copies via global atomics (16 adds/address).
__global__ __launch_bounds__(256, 4) void pass2(
    const float4* __restrict__ us4, int n4,
    const unsigned* __restrict__ uminInvSlots, const unsigned* __restrict__ umaxSlots,
    float* __restrict__ ghist) {
  __shared__ float hist[88 * 64];  // [row][lane], 22528 B
  __shared__ float smm[2];
  const int tid = threadIdx.x, lane = tid & 63;
  for (int i = tid; i < 88 * 64; i += 256) hist[i] = 0.f;
  if (tid < 64) {
    unsigned mnInv = waveMaxU(uminInvSlots[tid]);
    unsigned mxb = waveMaxU(umaxSlots[tid]);
    if (tid == 0) { smm[0] = __uint_as_float(~mnInv); smm[1] = __uint_as_float(mxb); }
  }
  __syncthreads();
  const float umin = smm[0], delta = smm[1] - smm[0];
  float th[21];
#pragma unroll
  for (int k = 0; k < 21; ++k) th[k] = fmaf(0.05f * (float)k, delta, umin);

  const int stride = gridDim.x * 256;
  for (int i = blockIdx.x * 256 + tid; i < n4; i += stride) {
    float4 v = us4[i];
    float vv[4] = {v.x, v.y, v.z, v.w};
#pragma unroll
    for (int q = 0; q < 4; ++q) {
      unsigned b = __float_as_uint(vv[q]);
      int rb = (b >> 31) ? 44 : 0;  // acc rows 0..43, inacc rows 44..87
      float u = __uint_as_float(b & 0x7fffffffu);
      // soft_T: log(num/den) = log(num)-log(den); clamp matches frac clamp
      float e = u * 0.4342944819f;  // u / ln(10)
      float lnum = __logf(e * 0.9f);
      float lden = __logf(fmaxf((1.f - e) * 0.1f, 1e-10f));
      float x = fmaxf(lnum - lden, -23.0258509f) * 100.f;
      float s = __builtin_amdgcn_rcpf(1.f + __expf(-x));                   // sigmoid
      float t = 1.f - 2.f * __builtin_amdgcn_rcpf(__expf(2.f * u) + 1.f);  // tanh
      float wc = (1.f - s) * (1.f - t), wu = s * t;
      int j = 0;  // j = #{k: u > th_k}; le[k] <=> k >= j
#pragma unroll
      for (int k = 0; k < 21; ++k) j += (u > th[k]) ? 1 : 0;
      atomicAdd(&hist[(rb + j) * 64 + lane], wc);        // ds_add_f32
      atomicAdd(&hist[(rb + 22 + j) * 64 + lane], wu);
    }
  }
  __syncthreads();
  // tree-reduce 64 columns per row
#pragma unroll
  for (int st = 32; st >= 1; st >>= 1) {
    for (int idx = tid; idx < 88 * st; idx += 256) {
      int r = idx / st, c = idx - r * st;
      hist[r * 64 + c] += hist[r * 64 + c + st];
    }
    __syncthreads();
  }
  int slot = blockIdx.x & 63;
  for (int r = tid; r < 88; r += 256)
    atomicAdd(&ghist[slot * 88 + r], hist[r * 64]);
}

// ---------------- pass 3: reduce 64 slot-copies + scalar slots, emit outputs
__global__ __launch_bounds__(256) void pass3(
    const float* __restrict__ ghist,
    const float* __restrict__ ceSlots, const float* __restrict__ focalSlots,
    float* __restrict__ out, float invN) {
  __shared__ float hr[88];
  __shared__ float scf[2];
  int tid = threadIdx.x;
  if (tid < 88) {
    float s = 0.f;
    for (int q = 0; q < 64; ++q) s += ghist[q * 88 + tid];  // coalesced across tid
    hr[tid] = s;
  }
  if (tid >= 128 && tid < 192) {
    int l = tid - 128;
    float ce = waveSum(ceSlots[l]);
    float fo = waveSum(focalSlots[l]);
    if (l == 0) { scf[0] = ce; scf[1] = fo; }
  }
  __syncthreads();
  if (tid == 0) {
    float H0[22], H1[22], H2[22], H3[22];
    float totAU = 0.f, totIU = 0.f;
    for (int j = 0; j < 22; ++j) {
      H0[j] = hr[j]; H1[j] = hr[22 + j]; H2[j] = hr[44 + j]; H3[j] = hr[66 + j];
      totAU += H1[j]; totIU += H3[j];
    }
    float n_ac = 0.f, n_ic = 0.f, n_au = totAU, n_iu = totIU;
    float auc = 0.f, prev = 0.f;
    for (int k = 0; k < 21; ++k) {
      n_ac += H0[k]; n_ic += H2[k];
      n_au -= H1[k]; n_iu -= H3[k];
      float avu = (n_ac + n_iu) / (n_ac + n_au + n_ic + n_iu + 1e-10f);
      if (k > 0) auc += (avu + prev) * 0.5f * 0.05f;
      prev = avu;
    }
    out[0] = -logf(fmaxf(auc, 1e-10f)) + scf[1] * invN;
    out[1] = scf[0] * invN;
  }
}

extern "C" void kernel_launch(void* const* d_in, const int* in_sizes, int n_in,
                              void* d_out, int out_size, void* d_ws, size_t ws_size,
                              hipStream_t stream) {
  const float* probs = (const float*)d_in[0];
  const float* y = (const float*)d_in[1];
  float* out = (float*)d_out;
  const int N = in_sizes[0] / C;

  // ws layout (floats): [0,64) uminInv slots, [64,128) umax slots,
  // [128,192) ce slots, [192,256) focal slots, [256,5888) ghist[64][88],
  // [5888, 5888+N) us  (5888*4 = 23552 B, 16B-aligned)
  float* wsf = (float*)d_ws;
  unsigned* uminInvSlots = (unsigned*)wsf;
  unsigned* umaxSlots = (unsigned*)(wsf + 64);
  float* ceSlots = wsf + 128;
  float* focalSlots = wsf + 192;
  float* ghist = wsf + 256;
  float* us = wsf + 5888;

  hipMemsetAsync(d_ws, 0, 5888 * sizeof(float), stream);  // all accumulators -> 0

  pass1<<<N / TILE, 256, 0, stream>>>(probs, y, us, uminInvSlots, umaxSlots,
                                      ceSlots, focalSlots);
  pass2<<<1024, 256, 0, stream>>>((const float4*)us, N / 4, uminInvSlots, umaxSlots,
                                  ghist);
  pass3<<<1, 256, 0, stream>>>(ghist, ceSlots, focalSlots, out, 1.0f / (float)N);
}